// Round 2
// baseline (582.085 us; speedup 1.0000x reference)
//
#include <hip/hip_runtime.h>

typedef __attribute__((ext_vector_type(8))) short  short8;
typedef __attribute__((ext_vector_type(4))) float  floatx4;
typedef __attribute__((ext_vector_type(2))) unsigned int uint2v;

#define NS 8   // L splits in attention

__device__ __forceinline__ unsigned short f2b(float f) {
  union { float f; unsigned u; } c; c.f = f;
  unsigned r = c.u + 0x7FFFu + ((c.u >> 16) & 1u);
  return (unsigned short)(r >> 16);
}

__device__ __forceinline__ float b2f(unsigned short u) {
  union { unsigned u; float f; } c; c.u = (unsigned)u << 16;
  return c.f;
}

__device__ __forceinline__ unsigned cvt_pk_bf16(float a, float b) {
  unsigned r;
  asm("v_cvt_pk_bf16_f32 %0, %1, %2" : "=v"(r) : "v"(a), "v"(b));
  return r;
}

__device__ __forceinline__ void async_copy16(const void* g, void* l) {
  __builtin_amdgcn_global_load_lds(
      (const __attribute__((address_space(1))) void*)g,
      (__attribute__((address_space(3))) void*)l, 16, 0, 0);
}

// ---------------- LayerNorm + bf16 cast: one block per row of 1024 ----------
__global__ __launch_bounds__(256) void ln_bf16_kernel(
    const float* __restrict__ src, const float* __restrict__ w,
    const float* __restrict__ bias, unsigned short* __restrict__ dst) {
  const size_t row = blockIdx.x;
  const int t = threadIdx.x;
  const float4 v = *(const float4*)&src[row * 1024 + t * 4];
  float s = v.x + v.y + v.z + v.w;
  float q = v.x * v.x + v.y * v.y + v.z * v.z + v.w * v.w;
#pragma unroll
  for (int m = 32; m >= 1; m >>= 1) {
    s += __shfl_xor(s, m, 64);
    q += __shfl_xor(q, m, 64);
  }
  __shared__ float ss[4], sq[4];
  if ((t & 63) == 0) { ss[t >> 6] = s; sq[t >> 6] = q; }
  __syncthreads();
  s = ss[0] + ss[1] + ss[2] + ss[3];
  q = sq[0] + sq[1] + sq[2] + sq[3];
  const float mu = s * (1.f / 1024.f);
  const float var = q * (1.f / 1024.f) - mu * mu;
  const float rs = rsqrtf(var + 1e-5f);
  const float4 wv = *(const float4*)&w[t * 4];
  const float4 bv = *(const float4*)&bias[t * 4];
  ushort4 o;
  o.x = f2b((v.x - mu) * rs * wv.x + bv.x);
  o.y = f2b((v.y - mu) * rs * wv.y + bv.y);
  o.z = f2b((v.z - mu) * rs * wv.z + bv.z);
  o.w = f2b((v.w - mu) * rs * wv.w + bv.w);
  *(ushort4*)&dst[row * 1024 + t * 4] = o;
}

// ---------------- f32 -> bf16 convert (weights) ------------------------------
__global__ __launch_bounds__(256) void conv_bf16_kernel(
    const float* __restrict__ src, unsigned short* __restrict__ dst) {
  const size_t i = (size_t)blockIdx.x * 256 + threadIdx.x;
  const float4 v = ((const float4*)src)[i];
  ushort4 o;
  o.x = f2b(v.x); o.y = f2b(v.y); o.z = f2b(v.z); o.w = f2b(v.w);
  ((ushort4*)dst)[i] = o;
}

// ---------------- V transpose: Vbf[bh][d][4096] = bf16(x[b][k][h*64+d]) -----
__global__ __launch_bounds__(256) void vtrans_kernel(
    const float* __restrict__ x, unsigned short* __restrict__ Vbf) {
  const int bh = blockIdx.x, kb = blockIdx.y;
  const int b = bh >> 4, h = bh & 15;
  const int t = threadIdx.x;
  const int d = t >> 2, kc = t & 3;
  const float* xp = x + (size_t)(b * 4096 + kb * 256) * 1024 + h * 64 + d;
  unsigned short* vp = Vbf + ((size_t)bh * 64 + d) * 4096 + kb * 256;
#pragma unroll
  for (int c = 0; c < 8; c++) {
    const int kk = c * 32 + kc * 8;
    short8 o;
#pragma unroll
    for (int j = 0; j < 8; j++)
      o[j] = (short)f2b(xp[(size_t)(kk + j) * 1024]);
    *(short8*)&vp[kk] = o;
  }
}

// ---------------- GEMM: out[m,n] = clip(A[m,:]·W[n,:] + bias[n]), bf16 ------
// Linear grid with XCD swizzle: nb = id&7 (each XCD owns one N-panel -> W-panel
// L2-resident), mb = id>>3. Epilogue bounces C through LDS (XOR-swizzled) so
// global stores are full 256B row segments (kills partial-line RMW fetch).
__global__ __launch_bounds__(256) void gemm_bt_kernel(
    const unsigned short* __restrict__ A, const unsigned short* __restrict__ W,
    const float* __restrict__ bias, unsigned short* __restrict__ out, int M) {
  __shared__ __align__(16) unsigned short smem[2][128 * 64];  // As, Bs; Cs reuse
  unsigned short* As = smem[0];
  unsigned short* Bs = smem[1];
  const int tid = threadIdx.x;
  const int wave = tid >> 6, lane = tid & 63;
  const int quad = lane >> 4, l16 = lane & 15;
  const int id = blockIdx.x;
  const size_t m0 = (size_t)(id >> 3) * 128;
  const int n0 = (id & 7) * 128;
  const int wm = (wave >> 1) * 64, wn = (wave & 1) * 64;
  const int r8 = lane >> 3, cvv = lane & 7;
  const int csrc = cvv ^ r8;

  floatx4 acc[4][4];
#pragma unroll
  for (int i = 0; i < 4; i++)
#pragma unroll
    for (int j = 0; j < 4; j++) acc[i][j] = (floatx4){0.f, 0.f, 0.f, 0.f};

  const unsigned short* gA = A + (m0 + wave * 32 + r8) * 1024 + csrc * 8;
  const unsigned short* gB = W + ((size_t)(n0 + wave * 32 + r8)) * 1024 + csrc * 8;

  for (int k0 = 0; k0 < 1024; k0 += 64) {
    __syncthreads();
#pragma unroll
    for (int it = 0; it < 4; ++it) {
      async_copy16(gA + (size_t)it * 8 * 1024 + k0, &As[(wave * 4 + it) * 512]);
      async_copy16(gB + (size_t)it * 8 * 1024 + k0, &Bs[(wave * 4 + it) * 512]);
    }
    __syncthreads();
#pragma unroll
    for (int kh = 0; kh < 2; ++kh) {
      short8 af[4], bf[4];
#pragma unroll
      for (int mi = 0; mi < 4; mi++) {
        int row = wm + mi * 16 + l16;
        af[mi] = *(const short8*)&As[row * 64 + (((kh * 4 + quad) ^ (row & 7)) * 8)];
      }
#pragma unroll
      for (int ni = 0; ni < 4; ni++) {
        int row = wn + ni * 16 + l16;
        bf[ni] = *(const short8*)&Bs[row * 64 + (((kh * 4 + quad) ^ (row & 7)) * 8)];
      }
#pragma unroll
      for (int mi = 0; mi < 4; mi++)
#pragma unroll
        for (int ni = 0; ni < 4; ni++)
          acc[mi][ni] = __builtin_amdgcn_mfma_f32_16x16x32_bf16(af[mi], bf[ni], acc[mi][ni], 0, 0, 0);
    }
  }

  // ---- epilogue: acc -> LDS (XOR swizzle) -> coalesced global stores
  __syncthreads();  // all LDS reads + global_load_lds writes drained
  unsigned short* Cs = smem[0];  // [128][128] bf16 = 32KB, reuses As+Bs
#pragma unroll
  for (int ni = 0; ni < 4; ni++) {
    int n = n0 + wn + ni * 16 + l16;
    float bv = bias[n];
    int c = wn + ni * 16 + l16;       // local col 0..127
#pragma unroll
    for (int mi = 0; mi < 4; mi++)
#pragma unroll
      for (int p = 0; p < 4; p++) {
        int r = wm + mi * 16 + quad * 4 + p;  // local row 0..127
        float v = acc[mi][ni][p] + bv;
        v = fminf(10.f, fmaxf(-10.f, v));
        int cc = c >> 3;
        Cs[r * 128 + ((cc ^ (r & 7)) * 8) + (c & 7)] = f2b(v);
      }
  }
  __syncthreads();
  // readback: per pass, wave covers 4 rows x 16 chunks = contiguous stores
#pragma unroll
  for (int i = 0; i < 8; ++i) {
    int r = (tid >> 4) + 16 * i;     // 0..127
    int cc = tid & 15;               // logical chunk 0..15
    short8 v = *(const short8*)&Cs[r * 128 + ((cc ^ (r & 7)) * 8)];
    *(short8*)&out[(m0 + r) * 1024 + n0 + cc * 8] = v;
  }
}

// ---------------- Attention: 32KB LDS (4 blocks/CU), mi-split Pw ------------
// grid (128 = b*h, NS). S^T orientation (mfma(K,Q)) + packed P staging.
// Pw holds only one mi-pair (32 q rows) at a time -> 16KB; Ks/Vs 8KB each.
// Epilogue bounces O through LDS for coalesced 128B-row stores.
__global__ __launch_bounds__(256) void attn_kernel(
    const unsigned short* __restrict__ Qp,   // [2048,1024] bf16
    const unsigned short* __restrict__ Kp,   // [32768,1024] bf16
    const unsigned short* __restrict__ Vbf,  // [128][64][4096] bf16
    unsigned short* __restrict__ Onum,       // [128][NS][256][64] bf16
    float* __restrict__ lpart) {             // [128][NS][256]
  const int bh = blockIdx.x, split = blockIdx.y;
  const int b = bh >> 4, h = bh & 15;
  const int tid = threadIdx.x, wave = tid >> 6, lane = tid & 63;
  const int quad = lane >> 4, l16 = lane & 15;
  const int r8 = lane >> 3, cvv = lane & 7, csrc = cvv ^ r8;

  __shared__ __align__(16) unsigned short smem[16384];  // 32KB total
  unsigned short* Ks = smem;          // [64][64] swizzled (8KB)
  unsigned short* Vs = smem + 4096;   // [64][64] swizzled (8KB)
  unsigned short* Pw = smem + 8192;   // [4 waves][32 q][64 kk] (16KB)

  short8 qf[4][2];
#pragma unroll
  for (int mi = 0; mi < 4; mi++)
#pragma unroll
    for (int kh = 0; kh < 2; kh++)
      qf[mi][kh] = *(const short8*)&Qp[(size_t)(b * 256 + wave * 64 + mi * 16 + l16) * 1024 +
                                       h * 64 + kh * 32 + quad * 8];

  floatx4 oacc[4][4];
  floatx4 lacc[4];
#pragma unroll
  for (int i = 0; i < 4; i++) {
    lacc[i] = (floatx4){0.f, 0.f, 0.f, 0.f};
#pragma unroll
    for (int j = 0; j < 4; j++) oacc[i][j] = (floatx4){0.f, 0.f, 0.f, 0.f};
  }
  short8 ones;
#pragma unroll
  for (int j = 0; j < 8; j++) ones[j] = (short)0x3F80;  // bf16 1.0

  const int kbase = split * (4096 / NS);
  // staging roles: waves 0,1 -> K rows [rowbase, +32); waves 2,3 -> V rows
  const int rowbase = (wave & 1) * 32;
  const bool isK = (wave < 2);
  const unsigned short* gK = Kp + ((size_t)(b * 4096 + kbase + rowbase + r8)) * 1024 +
                             h * 64 + csrc * 8;
  const unsigned short* gV = Vbf + ((size_t)(bh * 64 + rowbase + r8)) * 4096 +
                             kbase + csrc * 8;

  const int T = 4096 / NS / 64;  // 8 tiles per split
  unsigned short* Pb = Pw + wave * 2048;

  // prologue: prefetch tile 0 into registers
  uint4 stg[4];
  if (isK) {
#pragma unroll
    for (int it = 0; it < 4; ++it)
      stg[it] = *(const uint4*)&gK[((size_t)it * 8) * 1024];
  } else {
#pragma unroll
    for (int it = 0; it < 4; ++it)
      stg[it] = *(const uint4*)&gV[(size_t)it * 8 * 4096];
  }

  for (int t = 0; t < T; ++t) {
    __syncthreads();  // all waves done reading previous tile's LDS
    if (isK) {
#pragma unroll
      for (int it = 0; it < 4; ++it)
        *(uint4*)((char*)Ks + (rowbase + it * 8) * 128 + lane * 16) = stg[it];
    } else {
#pragma unroll
      for (int it = 0; it < 4; ++it)
        *(uint4*)((char*)Vs + (rowbase + it * 8) * 128 + lane * 16) = stg[it];
    }
    __syncthreads();
    // issue next tile's loads now; latency hides under compute below
    if (t + 1 < T) {
      if (isK) {
#pragma unroll
        for (int it = 0; it < 4; ++it)
          stg[it] = *(const uint4*)&gK[((size_t)(t + 1) * 64 + it * 8) * 1024];
      } else {
#pragma unroll
        for (int it = 0; it < 4; ++it)
          stg[it] = *(const uint4*)&gV[(size_t)it * 8 * 4096 + (t + 1) * 64];
      }
    }

#pragma unroll
    for (int mh = 0; mh < 2; ++mh) {
      // ---- QK^T (transposed) for mi pair {2mh, 2mh+1}
#pragma unroll
      for (int ni = 0; ni < 4; ++ni) {
        const int krow = ni * 16 + l16;
        const short8 kf0 = *(const short8*)&Ks[krow * 64 + ((quad ^ (krow & 7)) * 8)];
        const short8 kf1 = *(const short8*)&Ks[krow * 64 + (((4 + quad) ^ (krow & 7)) * 8)];
#pragma unroll
        for (int m2 = 0; m2 < 2; ++m2) {
          const int mi = mh * 2 + m2;
          floatx4 st = (floatx4){0.f, 0.f, 0.f, 0.f};
          st = __builtin_amdgcn_mfma_f32_16x16x32_bf16(kf0, qf[mi][0], st, 0, 0, 0);
          st = __builtin_amdgcn_mfma_f32_16x16x32_bf16(kf1, qf[mi][1], st, 0, 0, 0);
          const float C = 0.18033688011112042f;  // 0.125 * log2(e)
          float e0 = exp2f(st[0] * C);
          float e1 = exp2f(st[1] * C);
          float e2 = exp2f(st[2] * C);
          float e3 = exp2f(st[3] * C);
          unsigned lo = cvt_pk_bf16(e0, e1);
          unsigned hi = cvt_pk_bf16(e2, e3);
          const int qrow = m2 * 16 + l16;  // row within the 32-row Pw half
          const int chunk = (ni * 2 + (quad >> 1)) ^ (qrow & 7);
          uint2v wv; wv.x = lo; wv.y = hi;
          *(uint2v*)&Pb[qrow * 64 + chunk * 8 + (quad & 1) * 4] = wv;
        }
      }
      // ---- PV (+ row-sum via ones column) for this mi pair
#pragma unroll
      for (int kh = 0; kh < 2; ++kh) {
        short8 vf[4];
#pragma unroll
        for (int ni = 0; ni < 4; ni++) {
          int row = ni * 16 + l16;
          vf[ni] = *(const short8*)&Vs[row * 64 + (((kh * 4 + quad) ^ (row & 7)) * 8)];
        }
#pragma unroll
        for (int m2 = 0; m2 < 2; ++m2) {
          const int mi = mh * 2 + m2;
          const int qrow = m2 * 16 + l16;
          short8 pf = *(const short8*)&Pb[qrow * 64 + (((kh * 4 + quad) ^ (qrow & 7)) * 8)];
#pragma unroll
          for (int ni = 0; ni < 4; ni++)
            oacc[mi][ni] = __builtin_amdgcn_mfma_f32_16x16x32_bf16(pf, vf[ni], oacc[mi][ni], 0, 0, 0);
          lacc[mi] = __builtin_amdgcn_mfma_f32_16x16x32_bf16(pf, ones, lacc[mi], 0, 0, 0);
        }
      }
    }
  }

  // ---- epilogue: O through LDS for coalesced stores
  __syncthreads();  // everyone done with Ks/Vs/Pw
  unsigned short* Cs = smem;  // [256 q][64 d] bf16 = 32KB
#pragma unroll
  for (int mi = 0; mi < 4; mi++)
#pragma unroll
    for (int ni = 0; ni < 4; ni++)
#pragma unroll
      for (int p = 0; p < 4; p++) {
        int q = wave * 64 + mi * 16 + quad * 4 + p;
        int d = ni * 16 + l16;
        int cc = d >> 3;
        Cs[q * 64 + ((cc ^ (q & 7)) * 8) + (d & 7)] = f2b(oacc[mi][ni][p]);
      }
  __syncthreads();
  unsigned short* Ob = Onum + ((size_t)bh * NS + split) * 256 * 64;
#pragma unroll
  for (int i = 0; i < 8; ++i) {
    int q = (tid >> 3) + 32 * i;   // 0..255
    int cc = tid & 7;              // logical chunk 0..7
    short8 v = *(const short8*)&Cs[q * 64 + ((cc ^ (q & 7)) * 8)];
    *(short8*)&Ob[q * 64 + cc * 8] = v;
  }
  if (l16 == 0) {
    float* lb = lpart + ((size_t)bh * NS + split) * 256;
#pragma unroll
    for (int mi = 0; mi < 4; mi++)
#pragma unroll
      for (int p = 0; p < 4; p++)
        lb[wave * 64 + mi * 16 + quad * 4 + p] = lacc[mi][p];
  }
}

// ---------------- reduce: ho[b, h*64+d] = mean_q( sum_s O / sum_s l ) --------
__global__ __launch_bounds__(256) void reduce_heads_kernel(
    const unsigned short* __restrict__ Onum, const float* __restrict__ lpart,
    float* __restrict__ ho) {
  const int bh = blockIdx.x;
  const int t = threadIdx.x;
  __shared__ float ls[256];
  __shared__ float red[16][64];
  float l = 0.f;
#pragma unroll
  for (int s = 0; s < NS; s++) l += lpart[((size_t)bh * NS + s) * 256 + t];
  ls[t] = l;
  __syncthreads();
  const int d4 = t & 15, qg = t >> 4;  // d = d4*4, 16 q-groups of 16
  float4 part = {0.f, 0.f, 0.f, 0.f};
  for (int qi = 0; qi < 16; ++qi) {
    int q = qg * 16 + qi;
    float4 on = {0.f, 0.f, 0.f, 0.f};
#pragma unroll
    for (int s = 0; s < NS; s++) {
      ushort4 v = *(const ushort4*)&Onum[(((size_t)bh * NS + s) * 256 + q) * 64 + d4 * 4];
      on.x += b2f(v.x); on.y += b2f(v.y); on.z += b2f(v.z); on.w += b2f(v.w);
    }
    const float rl = 1.f / ls[q];
    part.x += on.x * rl; part.y += on.y * rl;
    part.z += on.z * rl; part.w += on.w * rl;
  }
  *(float4*)&red[qg][d4 * 4] = part;
  __syncthreads();
  if (t < 64) {
    float v = 0.f;
#pragma unroll
    for (int r = 0; r < 16; ++r) v += red[r][t];
    v *= (1.f / 256.f);
    int b = bh >> 4, h = bh & 15;
    ho[b * 1024 + h * 64 + t] = v;
  }
}

// ---------------- gs[b,c] = bo[c] + sum_k Wo[c,k] * ho[b,k] ------------------
__global__ __launch_bounds__(256) void wo_proj_kernel(
    const float* __restrict__ ho, const float* __restrict__ Wo,
    const float* __restrict__ bo, float* __restrict__ gs) {
  const int b = blockIdx.x >> 2, cg = blockIdx.x & 3;
  const int t = threadIdx.x;
  __shared__ float hs[1024];
#pragma unroll
  for (int i = 0; i < 4; i++) hs[t + i * 256] = ho[b * 1024 + t + i * 256];
  __syncthreads();
  const int c = cg * 256 + t;
  const float* wrow = Wo + (size_t)c * 1024;
  float acc = bo[c];
  for (int k = 0; k < 1024; k += 4) {
    float4 w4 = *(const float4*)&wrow[k];
    acc += w4.x * hs[k] + w4.y * hs[k + 1] + w4.z * hs[k + 2] + w4.w * hs[k + 3];
  }
  gs[b * 1024 + c] = acc;
}

// ---------------- out = x + a * gs[b,:] --------------------------------------
__global__ __launch_bounds__(256) void final_add_kernel(
    const float* __restrict__ x, const float* __restrict__ gs,
    const float* __restrict__ alpha, float* __restrict__ out) {
  const float a = 0.3f / (1.f + __expf(-alpha[0]));
  const size_t i4 = (size_t)blockIdx.x * 256 + threadIdx.x;
  const float4 xv = ((const float4*)x)[i4];
  const float4 g = *(const float4*)&gs[(i4 >> 20) * 1024 + (i4 & 255) * 4];
  float4 o;
  o.x = xv.x + a * g.x; o.y = xv.y + a * g.y;
  o.z = xv.z + a * g.z; o.w = xv.w + a * g.w;
  ((float4*)out)[i4] = o;
}

extern "C" void kernel_launch(void* const* d_in, const int* in_sizes, int n_in,
                              void* d_out, int out_size, void* d_ws, size_t ws_size,
                              hipStream_t stream) {
  const float* prompt = (const float*)d_in[0];
  const float* x      = (const float*)d_in[1];
  const float* lnqw   = (const float*)d_in[2];
  const float* lnqb   = (const float*)d_in[3];
  const float* lnkw   = (const float*)d_in[4];
  const float* lnkb   = (const float*)d_in[5];
  const float* Wq     = (const float*)d_in[6];
  const float* bq     = (const float*)d_in[7];
  const float* Wk     = (const float*)d_in[8];
  const float* bk     = (const float*)d_in[9];
  const float* Wo     = (const float*)d_in[10];
  const float* bo     = (const float*)d_in[11];
  const float* alpha  = (const float*)d_in[12];
  float* out = (float*)d_out;

  char* ws = (char*)d_ws;
  // kln and Vbf share the first 64 MB: kln fully consumed by the K-GEMM
  // before vtrans_kernel overwrites the region (stream-ordered).
  unsigned short* kln = (unsigned short*)(ws + 0);            // 64 MB
  unsigned short* Vbf = (unsigned short*)(ws + 0);            // 64 MB (after)
  unsigned short* qln = (unsigned short*)(ws + 67108864);     // 4 MB
  unsigned short* Wqb = (unsigned short*)(ws + 71303168);     // 2 MB
  unsigned short* Wkb = (unsigned short*)(ws + 73400320);     // 2 MB
  unsigned short* Qp  = (unsigned short*)(ws + 75497472);     // 4 MB
  float* lpart        = (float*)(ws + 79691776);              // 1 MB
  float* ho           = (float*)(ws + 80740352);              // 32 KB
  float* gs           = (float*)(ws + 80773120);              // 32 KB

  // d_out scratch: Kp (64 MB) + Onum bf16 (33.5 MB); both consumed before
  // final_add_kernel overwrites d_out.
  char* ob = (char*)d_out;
  unsigned short* Kp   = (unsigned short*)(ob + 0);           // 64 MB
  unsigned short* Onum = (unsigned short*)(ob + 67108864);    // 33.5 MB

  ln_bf16_kernel<<<32768, 256, 0, stream>>>(x, lnkw, lnkb, kln);
  ln_bf16_kernel<<<2048, 256, 0, stream>>>(prompt, lnqw, lnqb, qln);
  conv_bf16_kernel<<<1024, 256, 0, stream>>>(Wq, Wqb);
  conv_bf16_kernel<<<1024, 256, 0, stream>>>(Wk, Wkb);
  gemm_bt_kernel<<<128, 256, 0, stream>>>(qln, Wqb, bq, Qp, 2048);
  gemm_bt_kernel<<<2048, 256, 0, stream>>>(kln, Wkb, bk, Kp, 32768);
  vtrans_kernel<<<dim3(128, 16), 256, 0, stream>>>(x, Vbf);
  attn_kernel<<<dim3(128, NS), 256, 0, stream>>>(Qp, Kp, Vbf, Onum, lpart);
  reduce_heads_kernel<<<128, 256, 0, stream>>>(Onum, lpart, ho);
  wo_proj_kernel<<<32, 256, 0, stream>>>(ho, Wo, bo, gs);
  final_add_kernel<<<32768, 256, 0, stream>>>(x, gs, alpha, out);
}

// Round 4
// 581.044 us; speedup vs baseline: 1.0018x; 1.0018x over previous
//
#include <hip/hip_runtime.h>

typedef __attribute__((ext_vector_type(8))) short  short8;
typedef __attribute__((ext_vector_type(4))) float  floatx4;
typedef __attribute__((ext_vector_type(2))) unsigned int uint2v;

#define NS 8   // L splits in attention

__device__ __forceinline__ unsigned short f2b(float f) {
  union { float f; unsigned u; } c; c.f = f;
  unsigned r = c.u + 0x7FFFu + ((c.u >> 16) & 1u);
  return (unsigned short)(r >> 16);
}

__device__ __forceinline__ float b2f(unsigned short u) {
  union { unsigned u; float f; } c; c.u = (unsigned)u << 16;
  return c.f;
}

__device__ __forceinline__ unsigned cvt_pk_bf16(float a, float b) {
  unsigned r;
  asm("v_cvt_pk_bf16_f32 %0, %1, %2" : "=v"(r) : "v"(a), "v"(b));
  return r;
}

__device__ __forceinline__ void async_copy16(const void* g, void* l) {
  __builtin_amdgcn_global_load_lds(
      (const __attribute__((address_space(1))) void*)g,
      (__attribute__((address_space(3))) void*)l, 16, 0, 0);
}

// ---------------- LayerNorm + bf16 cast: one block per row of 1024 ----------
__global__ __launch_bounds__(256) void ln_bf16_kernel(
    const float* __restrict__ src, const float* __restrict__ w,
    const float* __restrict__ bias, unsigned short* __restrict__ dst) {
  const size_t row = blockIdx.x;
  const int t = threadIdx.x;
  const float4 v = *(const float4*)&src[row * 1024 + t * 4];
  float s = v.x + v.y + v.z + v.w;
  float q = v.x * v.x + v.y * v.y + v.z * v.z + v.w * v.w;
#pragma unroll
  for (int m = 32; m >= 1; m >>= 1) {
    s += __shfl_xor(s, m, 64);
    q += __shfl_xor(q, m, 64);
  }
  __shared__ float ss[4], sq[4];
  if ((t & 63) == 0) { ss[t >> 6] = s; sq[t >> 6] = q; }
  __syncthreads();
  s = ss[0] + ss[1] + ss[2] + ss[3];
  q = sq[0] + sq[1] + sq[2] + sq[3];
  const float mu = s * (1.f / 1024.f);
  const float var = q * (1.f / 1024.f) - mu * mu;
  const float rs = rsqrtf(var + 1e-5f);
  const float4 wv = *(const float4*)&w[t * 4];
  const float4 bv = *(const float4*)&bias[t * 4];
  ushort4 o;
  o.x = f2b((v.x - mu) * rs * wv.x + bv.x);
  o.y = f2b((v.y - mu) * rs * wv.y + bv.y);
  o.z = f2b((v.z - mu) * rs * wv.z + bv.z);
  o.w = f2b((v.w - mu) * rs * wv.w + bv.w);
  *(ushort4*)&dst[row * 1024 + t * 4] = o;
}

// ---------------- f32 -> bf16 convert (weights) ------------------------------
__global__ __launch_bounds__(256) void conv_bf16_kernel(
    const float* __restrict__ src, unsigned short* __restrict__ dst) {
  const size_t i = (size_t)blockIdx.x * 256 + threadIdx.x;
  const float4 v = ((const float4*)src)[i];
  ushort4 o;
  o.x = f2b(v.x); o.y = f2b(v.y); o.z = f2b(v.z); o.w = f2b(v.w);
  ((ushort4*)dst)[i] = o;
}

// ---------------- V transpose: Vbf[bh][d][4096] = bf16(x[b][k][h*64+d]) -----
// Coalesced float4 reads -> bf16 -> k-major LDS tile -> transposed readback ->
// coalesced dwordx4 stores (512B segments per d-row).
__global__ __launch_bounds__(256) void vtrans_kernel(
    const float* __restrict__ x, unsigned short* __restrict__ Vbf) {
  const int bh = blockIdx.x, kb = blockIdx.y;
  const int b = bh >> 4, h = bh & 15;
  const int t = threadIdx.x;
  __shared__ __align__(16) unsigned short tile[256][68];  // [k][d], +4 pad
  const int row16 = t >> 4, c4 = t & 15;
  const float* xp = x + ((size_t)(b * 4096 + kb * 256 + row16) * 1024) + h * 64 + c4 * 4;
#pragma unroll
  for (int pass = 0; pass < 16; ++pass) {
    const int k = pass * 16 + row16;
    float4 v = *(const float4*)&xp[(size_t)pass * 16 * 1024];
    ushort4 o;
    o.x = f2b(v.x); o.y = f2b(v.y); o.z = f2b(v.z); o.w = f2b(v.w);
    *(ushort4*)&tile[k][c4 * 4] = o;
  }
  __syncthreads();
  const int d = t >> 2, kc = t & 3;
  unsigned short* vp = Vbf + ((size_t)bh * 64 + d) * 4096 + kb * 256 + kc * 64;
#pragma unroll
  for (int j = 0; j < 8; ++j) {
    short8 o;
#pragma unroll
    for (int e = 0; e < 8; ++e) o[e] = (short)tile[kc * 64 + j * 8 + e][d];
    *(short8*)&vp[j * 8] = o;
  }
}

// ---------------- GEMM: out[m,n] = clip(A[m,:]·W[n,:] + bias[n]), bf16 ------
// XCD-chunked swizzle (m157 direction): work = (id&7)*chunk + id>>3, so each
// XCD owns a contiguous band of A-panels and the 8 n-blocks sharing an A-panel
// run consecutively on the SAME XCD (A fetched once per L2). Epilogue bounces
// C through LDS for full-row coalesced stores (no partial-line RMW).
__global__ __launch_bounds__(256) void gemm_bt_kernel(
    const unsigned short* __restrict__ A, const unsigned short* __restrict__ W,
    const float* __restrict__ bias, unsigned short* __restrict__ out, int M) {
  __shared__ __align__(16) unsigned short smem[2][128 * 64];  // As, Bs; Cs reuse
  unsigned short* As = smem[0];
  unsigned short* Bs = smem[1];
  const int tid = threadIdx.x;
  const int wave = tid >> 6, lane = tid & 63;
  const int quad = lane >> 4, l16 = lane & 15;
  const int chunk = gridDim.x >> 3;
  const int work = (blockIdx.x & 7) * chunk + (blockIdx.x >> 3);
  const size_t m0 = (size_t)(work >> 3) * 128;
  const int n0 = (work & 7) * 128;
  const int wm = (wave >> 1) * 64, wn = (wave & 1) * 64;
  const int r8 = lane >> 3, cvv = lane & 7;
  const int csrc = cvv ^ r8;

  floatx4 acc[4][4];
#pragma unroll
  for (int i = 0; i < 4; i++)
#pragma unroll
    for (int j = 0; j < 4; j++) acc[i][j] = (floatx4){0.f, 0.f, 0.f, 0.f};

  const unsigned short* gA = A + (m0 + wave * 32 + r8) * 1024 + csrc * 8;
  const unsigned short* gB = W + ((size_t)(n0 + wave * 32 + r8)) * 1024 + csrc * 8;

  for (int k0 = 0; k0 < 1024; k0 += 64) {
    __syncthreads();
#pragma unroll
    for (int it = 0; it < 4; ++it) {
      async_copy16(gA + (size_t)it * 8 * 1024 + k0, &As[(wave * 4 + it) * 512]);
      async_copy16(gB + (size_t)it * 8 * 1024 + k0, &Bs[(wave * 4 + it) * 512]);
    }
    __syncthreads();
#pragma unroll
    for (int kh = 0; kh < 2; ++kh) {
      short8 af[4], bf[4];
#pragma unroll
      for (int mi = 0; mi < 4; mi++) {
        int row = wm + mi * 16 + l16;
        af[mi] = *(const short8*)&As[row * 64 + (((kh * 4 + quad) ^ (row & 7)) * 8)];
      }
#pragma unroll
      for (int ni = 0; ni < 4; ni++) {
        int row = wn + ni * 16 + l16;
        bf[ni] = *(const short8*)&Bs[row * 64 + (((kh * 4 + quad) ^ (row & 7)) * 8)];
      }
#pragma unroll
      for (int mi = 0; mi < 4; mi++)
#pragma unroll
        for (int ni = 0; ni < 4; ni++)
          acc[mi][ni] = __builtin_amdgcn_mfma_f32_16x16x32_bf16(af[mi], bf[ni], acc[mi][ni], 0, 0, 0);
    }
  }

  // ---- epilogue: acc -> LDS (XOR swizzle) -> coalesced global stores
  __syncthreads();  // all LDS reads + global_load_lds writes drained
  unsigned short* Cs = smem[0];  // [128][128] bf16 = 32KB, reuses As+Bs
#pragma unroll
  for (int ni = 0; ni < 4; ni++) {
    int n = n0 + wn + ni * 16 + l16;
    float bv = bias[n];
    int c = wn + ni * 16 + l16;       // local col 0..127
#pragma unroll
    for (int mi = 0; mi < 4; mi++)
#pragma unroll
      for (int p = 0; p < 4; p++) {
        int r = wm + mi * 16 + quad * 4 + p;  // local row 0..127
        float v = acc[mi][ni][p] + bv;
        v = fminf(10.f, fmaxf(-10.f, v));
        int cc = c >> 3;
        Cs[r * 128 + ((cc ^ (r & 7)) * 8) + (c & 7)] = f2b(v);
      }
  }
  __syncthreads();
  // readback: per pass, wave covers 4 rows x 16 chunks = contiguous stores
#pragma unroll
  for (int i = 0; i < 8; ++i) {
    int r = (tid >> 4) + 16 * i;     // 0..127
    int cc = tid & 15;               // logical chunk 0..15
    short8 v = *(const short8*)&Cs[r * 128 + ((cc ^ (r & 7)) * 8)];
    *(short8*)&out[(m0 + r) * 1024 + n0 + cc * 8] = v;
  }
}

// ---------------- Attention: 32KB LDS (4 blocks/CU), mi-split Pw ------------
// grid (128 = b*h, NS). S^T orientation (mfma(K,Q)) + packed P staging.
// Pw holds only one mi-pair (32 q rows) at a time -> 16KB; Ks/Vs 8KB each.
// Epilogue bounces O through LDS for coalesced 128B-row stores.
__global__ __launch_bounds__(256) void attn_kernel(
    const unsigned short* __restrict__ Qp,   // [2048,1024] bf16
    const unsigned short* __restrict__ Kp,   // [32768,1024] bf16
    const unsigned short* __restrict__ Vbf,  // [128][64][4096] bf16
    unsigned short* __restrict__ Onum,       // [128][NS][256][64] bf16
    float* __restrict__ lpart) {             // [128][NS][256]
  const int bh = blockIdx.x, split = blockIdx.y;
  const int b = bh >> 4, h = bh & 15;
  const int tid = threadIdx.x, wave = tid >> 6, lane = tid & 63;
  const int quad = lane >> 4, l16 = lane & 15;
  const int r8 = lane >> 3, cvv = lane & 7, csrc = cvv ^ r8;

  __shared__ __align__(16) unsigned short smem[16384];  // 32KB total
  unsigned short* Ks = smem;          // [64][64] swizzled (8KB)
  unsigned short* Vs = smem + 4096;   // [64][64] swizzled (8KB)
  unsigned short* Pw = smem + 8192;   // [4 waves][32 q][64 kk] (16KB)

  short8 qf[4][2];
#pragma unroll
  for (int mi = 0; mi < 4; mi++)
#pragma unroll
    for (int kh = 0; kh < 2; kh++)
      qf[mi][kh] = *(const short8*)&Qp[(size_t)(b * 256 + wave * 64 + mi * 16 + l16) * 1024 +
                                       h * 64 + kh * 32 + quad * 8];

  floatx4 oacc[4][4];
  floatx4 lacc[4];
#pragma unroll
  for (int i = 0; i < 4; i++) {
    lacc[i] = (floatx4){0.f, 0.f, 0.f, 0.f};
#pragma unroll
    for (int j = 0; j < 4; j++) oacc[i][j] = (floatx4){0.f, 0.f, 0.f, 0.f};
  }
  short8 ones;
#pragma unroll
  for (int j = 0; j < 8; j++) ones[j] = (short)0x3F80;  // bf16 1.0

  const int kbase = split * (4096 / NS);
  // staging roles: waves 0,1 -> K rows [rowbase, +32); waves 2,3 -> V rows
  const int rowbase = (wave & 1) * 32;
  const bool isK = (wave < 2);
  const unsigned short* gK = Kp + ((size_t)(b * 4096 + kbase + rowbase + r8)) * 1024 +
                             h * 64 + csrc * 8;
  const unsigned short* gV = Vbf + ((size_t)(bh * 64 + rowbase + r8)) * 4096 +
                             kbase + csrc * 8;

  const int T = 4096 / NS / 64;  // 8 tiles per split
  unsigned short* Pb = Pw + wave * 2048;

  // prologue: prefetch tile 0 into registers
  uint4 stg[4];
  if (isK) {
#pragma unroll
    for (int it = 0; it < 4; ++it)
      stg[it] = *(const uint4*)&gK[((size_t)it * 8) * 1024];
  } else {
#pragma unroll
    for (int it = 0; it < 4; ++it)
      stg[it] = *(const uint4*)&gV[(size_t)it * 8 * 4096];
  }

  for (int t = 0; t < T; ++t) {
    __syncthreads();  // all waves done reading previous tile's LDS
    if (isK) {
#pragma unroll
      for (int it = 0; it < 4; ++it)
        *(uint4*)((char*)Ks + (rowbase + it * 8) * 128 + lane * 16) = stg[it];
    } else {
#pragma unroll
      for (int it = 0; it < 4; ++it)
        *(uint4*)((char*)Vs + (rowbase + it * 8) * 128 + lane * 16) = stg[it];
    }
    __syncthreads();
    // issue next tile's loads now; latency hides under compute below
    if (t + 1 < T) {
      if (isK) {
#pragma unroll
        for (int it = 0; it < 4; ++it)
          stg[it] = *(const uint4*)&gK[((size_t)(t + 1) * 64 + it * 8) * 1024];
      } else {
#pragma unroll
        for (int it = 0; it < 4; ++it)
          stg[it] = *(const uint4*)&gV[(size_t)it * 8 * 4096 + (t + 1) * 64];
      }
    }

#pragma unroll
    for (int mh = 0; mh < 2; ++mh) {
      // ---- QK^T (transposed) for mi pair {2mh, 2mh+1}
#pragma unroll
      for (int ni = 0; ni < 4; ++ni) {
        const int krow = ni * 16 + l16;
        const short8 kf0 = *(const short8*)&Ks[krow * 64 + ((quad ^ (krow & 7)) * 8)];
        const short8 kf1 = *(const short8*)&Ks[krow * 64 + (((4 + quad) ^ (krow & 7)) * 8)];
#pragma unroll
        for (int m2 = 0; m2 < 2; ++m2) {
          const int mi = mh * 2 + m2;
          floatx4 st = (floatx4){0.f, 0.f, 0.f, 0.f};
          st = __builtin_amdgcn_mfma_f32_16x16x32_bf16(kf0, qf[mi][0], st, 0, 0, 0);
          st = __builtin_amdgcn_mfma_f32_16x16x32_bf16(kf1, qf[mi][1], st, 0, 0, 0);
          const float C = 0.18033688011112042f;  // 0.125 * log2(e)
          float e0 = exp2f(st[0] * C);
          float e1 = exp2f(st[1] * C);
          float e2 = exp2f(st[2] * C);
          float e3 = exp2f(st[3] * C);
          unsigned lo = cvt_pk_bf16(e0, e1);
          unsigned hi = cvt_pk_bf16(e2, e3);
          const int qrow = m2 * 16 + l16;  // row within the 32-row Pw half
          const int chunk = (ni * 2 + (quad >> 1)) ^ (qrow & 7);
          uint2v wv; wv.x = lo; wv.y = hi;
          *(uint2v*)&Pb[qrow * 64 + chunk * 8 + (quad & 1) * 4] = wv;
        }
      }
      // ---- PV (+ row-sum via ones column) for this mi pair
#pragma unroll
      for (int kh = 0; kh < 2; ++kh) {
        short8 vf[4];
#pragma unroll
        for (int ni = 0; ni < 4; ni++) {
          int row = ni * 16 + l16;
          vf[ni] = *(const short8*)&Vs[row * 64 + (((kh * 4 + quad) ^ (row & 7)) * 8)];
        }
#pragma unroll
        for (int m2 = 0; m2 < 2; ++m2) {
          const int mi = mh * 2 + m2;
          const int qrow = m2 * 16 + l16;
          short8 pf = *(const short8*)&Pb[qrow * 64 + (((kh * 4 + quad) ^ (qrow & 7)) * 8)];
#pragma unroll
          for (int ni = 0; ni < 4; ni++)
            oacc[mi][ni] = __builtin_amdgcn_mfma_f32_16x16x32_bf16(pf, vf[ni], oacc[mi][ni], 0, 0, 0);
          lacc[mi] = __builtin_amdgcn_mfma_f32_16x16x32_bf16(pf, ones, lacc[mi], 0, 0, 0);
        }
      }
    }
  }

  // ---- epilogue: O through LDS for coalesced stores
  __syncthreads();  // everyone done with Ks/Vs/Pw
  unsigned short* Cs = smem;  // [256 q][64 d] bf16 = 32KB
#pragma unroll
  for (int mi = 0; mi < 4; mi++)
#pragma unroll
    for (int ni = 0; ni < 4; ni++)
#pragma unroll
      for (int p = 0; p < 4; p++) {
        int q = wave * 64 + mi * 16 + quad * 4 + p;
        int d = ni * 16 + l16;
        int cc = d >> 3;
        Cs[q * 64 + ((cc ^ (q & 7)) * 8) + (d & 7)] = f2b(oacc[mi][ni][p]);
      }
  __syncthreads();
  unsigned short* Ob = Onum + ((size_t)bh * NS + split) * 256 * 64;
#pragma unroll
  for (int i = 0; i < 8; ++i) {
    int q = (tid >> 3) + 32 * i;   // 0..255
    int cc = tid & 7;              // logical chunk 0..7
    short8 v = *(const short8*)&Cs[q * 64 + ((cc ^ (q & 7)) * 8)];
    *(short8*)&Ob[q * 64 + cc * 8] = v;
  }
  if (l16 == 0) {
    float* lb = lpart + ((size_t)bh * NS + split) * 256;
#pragma unroll
    for (int mi = 0; mi < 4; mi++)
#pragma unroll
      for (int p = 0; p < 4; p++)
        lb[wave * 64 + mi * 16 + quad * 4 + p] = lacc[mi][p];
  }
}

// ---------------- reduce: ho[b, h*64+d] = mean_q( sum_s O / sum_s l ) --------
__global__ __launch_bounds__(256) void reduce_heads_kernel(
    const unsigned short* __restrict__ Onum, const float* __restrict__ lpart,
    float* __restrict__ ho) {
  const int bh = blockIdx.x;
  const int t = threadIdx.x;
  __shared__ float ls[256];
  __shared__ float red[16][64];
  float l = 0.f;
#pragma unroll
  for (int s = 0; s < NS; s++) l += lpart[((size_t)bh * NS + s) * 256 + t];
  ls[t] = l;
  __syncthreads();
  const int d4 = t & 15, qg = t >> 4;  // d = d4*4, 16 q-groups of 16
  float4 part = {0.f, 0.f, 0.f, 0.f};
  for (int qi = 0; qi < 16; ++qi) {
    int q = qg * 16 + qi;
    float4 on = {0.f, 0.f, 0.f, 0.f};
#pragma unroll
    for (int s = 0; s < NS; s++) {
      ushort4 v = *(const ushort4*)&Onum[(((size_t)bh * NS + s) * 256 + q) * 64 + d4 * 4];
      on.x += b2f(v.x); on.y += b2f(v.y); on.z += b2f(v.z); on.w += b2f(v.w);
    }
    const float rl = 1.f / ls[q];
    part.x += on.x * rl; part.y += on.y * rl;
    part.z += on.z * rl; part.w += on.w * rl;
  }
  *(float4*)&red[qg][d4 * 4] = part;
  __syncthreads();
  if (t < 64) {
    float v = 0.f;
#pragma unroll
    for (int r = 0; r < 16; ++r) v += red[r][t];
    v *= (1.f / 256.f);
    int b = bh >> 4, h = bh & 15;
    ho[b * 1024 + h * 64 + t] = v;
  }
}

// ---------------- gs[b,c] = bo[c] + sum_k Wo[c,k] * ho[b,k] ------------------
__global__ __launch_bounds__(256) void wo_proj_kernel(
    const float* __restrict__ ho, const float* __restrict__ Wo,
    const float* __restrict__ bo, float* __restrict__ gs) {
  const int b = blockIdx.x >> 2, cg = blockIdx.x & 3;
  const int t = threadIdx.x;
  __shared__ float hs[1024];
#pragma unroll
  for (int i = 0; i < 4; i++) hs[t + i * 256] = ho[b * 1024 + t + i * 256];
  __syncthreads();
  const int c = cg * 256 + t;
  const float* wrow = Wo + (size_t)c * 1024;
  float acc = bo[c];
  for (int k = 0; k < 1024; k += 4) {
    float4 w4 = *(const float4*)&wrow[k];
    acc += w4.x * hs[k] + w4.y * hs[k + 1] + w4.z * hs[k + 2] + w4.w * hs[k + 3];
  }
  gs[b * 1024 + c] = acc;
}

// ---------------- out = x + a * gs[b,:] --------------------------------------
__global__ __launch_bounds__(256) void final_add_kernel(
    const float* __restrict__ x, const float* __restrict__ gs,
    const float* __restrict__ alpha, float* __restrict__ out) {
  const float a = 0.3f / (1.f + __expf(-alpha[0]));
  const size_t i4 = (size_t)blockIdx.x * 256 + threadIdx.x;
  const float4 xv = ((const float4*)x)[i4];
  const float4 g = *(const float4*)&gs[(i4 >> 20) * 1024 + (i4 & 255) * 4];
  float4 o;
  o.x = xv.x + a * g.x; o.y = xv.y + a * g.y;
  o.z = xv.z + a * g.z; o.w = xv.w + a * g.w;
  ((float4*)out)[i4] = o;
}

extern "C" void kernel_launch(void* const* d_in, const int* in_sizes, int n_in,
                              void* d_out, int out_size, void* d_ws, size_t ws_size,
                              hipStream_t stream) {
  const float* prompt = (const float*)d_in[0];
  const float* x      = (const float*)d_in[1];
  const float* lnqw   = (const float*)d_in[2];
  const float* lnqb   = (const float*)d_in[3];
  const float* lnkw   = (const float*)d_in[4];
  const float* lnkb   = (const float*)d_in[5];
  const float* Wq     = (const float*)d_in[6];
  const float* bq     = (const float*)d_in[7];
  const float* Wk     = (const float*)d_in[8];
  const float* bk     = (const float*)d_in[9];
  const float* Wo     = (const float*)d_in[10];
  const float* bo     = (const float*)d_in[11];
  const float* alpha  = (const float*)d_in[12];
  float* out = (float*)d_out;

  char* ws = (char*)d_ws;
  // kln and Vbf share the first 64 MB: kln fully consumed by the K-GEMM
  // before vtrans_kernel overwrites the region (stream-ordered).
  unsigned short* kln = (unsigned short*)(ws + 0);            // 64 MB
  unsigned short* Vbf = (unsigned short*)(ws + 0);            // 64 MB (after)
  unsigned short* qln = (unsigned short*)(ws + 67108864);     // 4 MB
  unsigned short* Wqb = (unsigned short*)(ws + 71303168);     // 2 MB
  unsigned short* Wkb = (unsigned short*)(ws + 73400320);     // 2 MB
  unsigned short* Qp  = (unsigned short*)(ws + 75497472);     // 4 MB
  float* lpart        = (float*)(ws + 79691776);              // 1 MB
  float* ho           = (float*)(ws + 80740352);              // 32 KB
  float* gs           = (float*)(ws + 80773120);              // 32 KB

  // d_out scratch: Kp (64 MB) + Onum bf16 (33.5 MB); both consumed before
  // final_add_kernel overwrites d_out.
  char* ob = (char*)d_out;
  unsigned short* Kp   = (unsigned short*)(ob + 0);           // 64 MB
  unsigned short* Onum = (unsigned short*)(ob + 67108864);    // 33.5 MB

  ln_bf16_kernel<<<32768, 256, 0, stream>>>(x, lnkw, lnkb, kln);
  ln_bf16_kernel<<<2048, 256, 0, stream>>>(prompt, lnqw, lnqb, qln);
  conv_bf16_kernel<<<1024, 256, 0, stream>>>(Wq, Wqb);
  conv_bf16_kernel<<<1024, 256, 0, stream>>>(Wk, Wkb);
  gemm_bt_kernel<<<128, 256, 0, stream>>>(qln, Wqb, bq, Qp, 2048);
  gemm_bt_kernel<<<2048, 256, 0, stream>>>(kln, Wkb, bk, Kp, 32768);
  vtrans_kernel<<<dim3(128, 16), 256, 0, stream>>>(x, Vbf);
  attn_kernel<<<dim3(128, NS), 256, 0, stream>>>(Qp, Kp, Vbf, Onum, lpart);
  reduce_heads_kernel<<<128, 256, 0, stream>>>(Onum, lpart, ho);
  wo_proj_kernel<<<32, 256, 0, stream>>>(ho, Wo, bo, gs);
  final_add_kernel<<<32768, 256, 0, stream>>>(x, gs, alpha, out);
}

// Round 5
// 560.246 us; speedup vs baseline: 1.0390x; 1.0371x over previous
//
#include <hip/hip_runtime.h>

typedef __attribute__((ext_vector_type(8))) short  short8;
typedef __attribute__((ext_vector_type(4))) float  floatx4;
typedef __attribute__((ext_vector_type(2))) unsigned int uint2v;
typedef __attribute__((ext_vector_type(4))) unsigned int uintx4;

#define NS 8   // L splits in attention

__device__ __forceinline__ unsigned short f2b(float f) {
  union { float f; unsigned u; } c; c.f = f;
  unsigned r = c.u + 0x7FFFu + ((c.u >> 16) & 1u);
  return (unsigned short)(r >> 16);
}

__device__ __forceinline__ float b2f(unsigned short u) {
  union { unsigned u; float f; } c; c.u = (unsigned)u << 16;
  return c.f;
}

__device__ __forceinline__ unsigned cvt_pk_bf16(float a, float b) {
  unsigned r;
  asm("v_cvt_pk_bf16_f32 %0, %1, %2" : "=v"(r) : "v"(a), "v"(b));
  return r;
}

__device__ __forceinline__ uint2v permswap32(unsigned a, unsigned b) {
  return __builtin_amdgcn_permlane32_swap(a, b, false, false);
}

__device__ __forceinline__ void async_copy16(const void* g, void* l) {
  __builtin_amdgcn_global_load_lds(
      (const __attribute__((address_space(1))) void*)g,
      (__attribute__((address_space(3))) void*)l, 16, 0, 0);
}

// ---------------- LayerNorm + bf16 cast: one block per row of 1024 ----------
__global__ __launch_bounds__(256) void ln_bf16_kernel(
    const float* __restrict__ src, const float* __restrict__ w,
    const float* __restrict__ bias, unsigned short* __restrict__ dst) {
  const size_t row = blockIdx.x;
  const int t = threadIdx.x;
  const float4 v = *(const float4*)&src[row * 1024 + t * 4];
  float s = v.x + v.y + v.z + v.w;
  float q = v.x * v.x + v.y * v.y + v.z * v.z + v.w * v.w;
#pragma unroll
  for (int m = 32; m >= 1; m >>= 1) {
    s += __shfl_xor(s, m, 64);
    q += __shfl_xor(q, m, 64);
  }
  __shared__ float ss[4], sq[4];
  if ((t & 63) == 0) { ss[t >> 6] = s; sq[t >> 6] = q; }
  __syncthreads();
  s = ss[0] + ss[1] + ss[2] + ss[3];
  q = sq[0] + sq[1] + sq[2] + sq[3];
  const float mu = s * (1.f / 1024.f);
  const float var = q * (1.f / 1024.f) - mu * mu;
  const float rs = rsqrtf(var + 1e-5f);
  const float4 wv = *(const float4*)&w[t * 4];
  const float4 bv = *(const float4*)&bias[t * 4];
  ushort4 o;
  o.x = f2b((v.x - mu) * rs * wv.x + bv.x);
  o.y = f2b((v.y - mu) * rs * wv.y + bv.y);
  o.z = f2b((v.z - mu) * rs * wv.z + bv.z);
  o.w = f2b((v.w - mu) * rs * wv.w + bv.w);
  *(ushort4*)&dst[row * 1024 + t * 4] = o;
}

// ---------------- f32 -> bf16 convert (weights) ------------------------------
__global__ __launch_bounds__(256) void conv_bf16_kernel(
    const float* __restrict__ src, unsigned short* __restrict__ dst) {
  const size_t i = (size_t)blockIdx.x * 256 + threadIdx.x;
  const float4 v = ((const float4*)src)[i];
  ushort4 o;
  o.x = f2b(v.x); o.y = f2b(v.y); o.z = f2b(v.z); o.w = f2b(v.w);
  ((ushort4*)dst)[i] = o;
}

// ---------------- V transpose: Vbf[bh][d][4096] = bf16(x[b][k][h*64+d]) -----
__global__ __launch_bounds__(256) void vtrans_kernel(
    const float* __restrict__ x, unsigned short* __restrict__ Vbf) {
  const int bh = blockIdx.x, kb = blockIdx.y;
  const int b = bh >> 4, h = bh & 15;
  const int t = threadIdx.x;
  __shared__ __align__(16) unsigned short tile[256][68];  // [k][d], +4 pad
  const int row16 = t >> 4, c4 = t & 15;
  const float* xp = x + ((size_t)(b * 4096 + kb * 256 + row16) * 1024) + h * 64 + c4 * 4;
#pragma unroll
  for (int pass = 0; pass < 16; ++pass) {
    const int k = pass * 16 + row16;
    float4 v = *(const float4*)&xp[(size_t)pass * 16 * 1024];
    ushort4 o;
    o.x = f2b(v.x); o.y = f2b(v.y); o.z = f2b(v.z); o.w = f2b(v.w);
    *(ushort4*)&tile[k][c4 * 4] = o;
  }
  __syncthreads();
  const int d = t >> 2, kc = t & 3;
  unsigned short* vp = Vbf + ((size_t)bh * 64 + d) * 4096 + kb * 256 + kc * 64;
#pragma unroll
  for (int j = 0; j < 8; ++j) {
    short8 o;
#pragma unroll
    for (int e = 0; e < 8; ++e) o[e] = (short)tile[kc * 64 + j * 8 + e][d];
    *(short8*)&vp[j * 8] = o;
  }
}

// ---------------- GEMM: out[m,n] = clip(A[m,:]·W[n,:] + bias[n]), bf16 ------
__global__ __launch_bounds__(256) void gemm_bt_kernel(
    const unsigned short* __restrict__ A, const unsigned short* __restrict__ W,
    const float* __restrict__ bias, unsigned short* __restrict__ out, int M) {
  __shared__ __align__(16) unsigned short smem[2][128 * 64];  // As, Bs; Cs reuse
  unsigned short* As = smem[0];
  unsigned short* Bs = smem[1];
  const int tid = threadIdx.x;
  const int wave = tid >> 6, lane = tid & 63;
  const int quad = lane >> 4, l16 = lane & 15;
  const int chunk = gridDim.x >> 3;
  const int work = (blockIdx.x & 7) * chunk + (blockIdx.x >> 3);
  const size_t m0 = (size_t)(work >> 3) * 128;
  const int n0 = (work & 7) * 128;
  const int wm = (wave >> 1) * 64, wn = (wave & 1) * 64;
  const int r8 = lane >> 3, cvv = lane & 7;
  const int csrc = cvv ^ r8;

  floatx4 acc[4][4];
#pragma unroll
  for (int i = 0; i < 4; i++)
#pragma unroll
    for (int j = 0; j < 4; j++) acc[i][j] = (floatx4){0.f, 0.f, 0.f, 0.f};

  const unsigned short* gA = A + (m0 + wave * 32 + r8) * 1024 + csrc * 8;
  const unsigned short* gB = W + ((size_t)(n0 + wave * 32 + r8)) * 1024 + csrc * 8;

  for (int k0 = 0; k0 < 1024; k0 += 64) {
    __syncthreads();
#pragma unroll
    for (int it = 0; it < 4; ++it) {
      async_copy16(gA + (size_t)it * 8 * 1024 + k0, &As[(wave * 4 + it) * 512]);
      async_copy16(gB + (size_t)it * 8 * 1024 + k0, &Bs[(wave * 4 + it) * 512]);
    }
    __syncthreads();
#pragma unroll
    for (int kh = 0; kh < 2; ++kh) {
      short8 af[4], bf[4];
#pragma unroll
      for (int mi = 0; mi < 4; mi++) {
        int row = wm + mi * 16 + l16;
        af[mi] = *(const short8*)&As[row * 64 + (((kh * 4 + quad) ^ (row & 7)) * 8)];
      }
#pragma unroll
      for (int ni = 0; ni < 4; ni++) {
        int row = wn + ni * 16 + l16;
        bf[ni] = *(const short8*)&Bs[row * 64 + (((kh * 4 + quad) ^ (row & 7)) * 8)];
      }
#pragma unroll
      for (int mi = 0; mi < 4; mi++)
#pragma unroll
        for (int ni = 0; ni < 4; ni++)
          acc[mi][ni] = __builtin_amdgcn_mfma_f32_16x16x32_bf16(af[mi], bf[ni], acc[mi][ni], 0, 0, 0);
    }
  }

  // ---- epilogue: acc -> LDS (XOR swizzle) -> coalesced global stores
  __syncthreads();
  unsigned short* Cs = smem[0];  // [128][128] bf16 = 32KB
#pragma unroll
  for (int ni = 0; ni < 4; ni++) {
    int n = n0 + wn + ni * 16 + l16;
    float bv = bias[n];
    int c = wn + ni * 16 + l16;
#pragma unroll
    for (int mi = 0; mi < 4; mi++)
#pragma unroll
      for (int p = 0; p < 4; p++) {
        int r = wm + mi * 16 + quad * 4 + p;
        float v = acc[mi][ni][p] + bv;
        v = fminf(10.f, fmaxf(-10.f, v));
        int cc = c >> 3;
        Cs[r * 128 + ((cc ^ (r & 7)) * 8) + (c & 7)] = f2b(v);
      }
  }
  __syncthreads();
#pragma unroll
  for (int i = 0; i < 8; ++i) {
    int r = (tid >> 4) + 16 * i;
    int cc = tid & 15;
    short8 v = *(const short8*)&Cs[r * 128 + ((cc ^ (r & 7)) * 8)];
    *(short8*)&out[(m0 + r) * 1024 + n0 + cc * 8] = v;
  }
}

// ---------------- Attention: in-register P via permlane32_swap --------------
// grid (128 = b*h, NS). S^T orientation with PERMUTED K-row fragment loading:
//   krow(ni,l16) = 32*b3 + 16*(ni>>1) + 8*b2 + 4*(ni&1) + (l16&3)
// so MFMA emits S^T with kk = 32*(qd>>1)+16*(ni>>1)+8*(qd&1)+4*(ni&1)+p.
// Then one permlane32_swap(w[nil][h], w[nil+2][h]) per dword pair yields BOTH
// PV A-fragments (result.x -> kh=0 slot 2*nil+h, result.y -> kh=1) with no
// LDS round trip. K/V double-buffered via global_load_lds: ONE barrier/tile.
// Row-sum l via VALU adds + end-of-kernel quad shfl reduce (no ones-MFMA).
__global__ __launch_bounds__(256) void attn_kernel(
    const unsigned short* __restrict__ Qp,   // [2048,1024] bf16
    const unsigned short* __restrict__ Kp,   // [32768,1024] bf16
    const unsigned short* __restrict__ Vbf,  // [128][64][4096] bf16
    unsigned short* __restrict__ Onum,       // [128][NS][256][64] bf16
    float* __restrict__ lpart) {             // [128][NS][256]
  const int bh = blockIdx.x, split = blockIdx.y;
  const int b = bh >> 4, h = bh & 15;
  const int tid = threadIdx.x, wave = tid >> 6, lane = tid & 63;
  const int quad = lane >> 4, l16 = lane & 15;
  const int r8 = lane >> 3, cvv = lane & 7, csrc = cvv ^ r8;

  __shared__ __align__(16) unsigned short smem[2][8192];  // [buf][K 4096 | V 4096]

  short8 qf[4][2];
#pragma unroll
  for (int mi = 0; mi < 4; mi++)
#pragma unroll
    for (int kh = 0; kh < 2; kh++)
      qf[mi][kh] = *(const short8*)&Qp[(size_t)(b * 256 + wave * 64 + mi * 16 + l16) * 1024 +
                                       h * 64 + kh * 32 + quad * 8];

  floatx4 oacc[4][4];
#pragma unroll
  for (int i = 0; i < 4; i++)
#pragma unroll
    for (int j = 0; j < 4; j++) oacc[i][j] = (floatx4){0.f, 0.f, 0.f, 0.f};
  float lsum[4] = {0.f, 0.f, 0.f, 0.f};

  // LDS read offsets (shorts). kh=1 variant = kh=0 ^ 32 (chunk XOR 4).
  int koff[4], voff[4];
#pragma unroll
  for (int ni = 0; ni < 4; ++ni) {
    const int krow = ((l16 >> 3) << 5) | ((ni >> 1) << 4) | (((l16 >> 2) & 1) << 3) |
                     ((ni & 1) << 2) | (l16 & 3);
    koff[ni] = krow * 64 + ((quad ^ (krow & 7)) * 8);
    const int vrow = ni * 16 + l16;
    voff[ni] = 4096 + vrow * 64 + ((quad ^ (vrow & 7)) * 8);
  }

  const int kbase = split * 512;
  const int rowbase = (wave & 1) * 32;
  const bool isK = (wave < 2);
  // unified staging source: per-lane global addr, wave-uniform LDS dest
  const unsigned short* gsrc =
      isK ? Kp + ((size_t)(b * 4096 + kbase + rowbase + r8)) * 1024 + h * 64 + csrc * 8
          : Vbf + ((size_t)(bh * 64 + rowbase + r8)) * 4096 + kbase + csrc * 8;
  const size_t itstep = isK ? (size_t)8 * 1024 : (size_t)8 * 4096;
  const size_t tstep  = isK ? (size_t)64 * 1024 : (size_t)64;
  const int ldsbase = (isK ? 0 : 4096) + rowbase * 64;

  // prologue: stage tile 0 into buf 0
#pragma unroll
  for (int it = 0; it < 4; ++it)
    async_copy16(gsrc + it * itstep, &smem[0][ldsbase + it * 8 * 64]);
  __syncthreads();

  for (int t = 0; t < 8; ++t) {
    if (t < 7) {
      unsigned short* dB = smem[(t + 1) & 1];
#pragma unroll
      for (int it = 0; it < 4; ++it)
        async_copy16(gsrc + (size_t)(t + 1) * tstep + it * itstep,
                     &dB[ldsbase + it * 8 * 64]);
    }
    const unsigned short* Bf = smem[t & 1];

#pragma unroll
    for (int mh = 0; mh < 2; ++mh) {
      unsigned pa0[2][4], pa1[2][4];
#pragma unroll
      for (int nl = 0; nl < 2; ++nl) {
        const short8 ka0 = *(const short8*)&Bf[koff[nl]];
        const short8 ka1 = *(const short8*)&Bf[koff[nl] ^ 32];
        const short8 kb0 = *(const short8*)&Bf[koff[nl + 2]];
        const short8 kb1 = *(const short8*)&Bf[koff[nl + 2] ^ 32];
#pragma unroll
        for (int m2 = 0; m2 < 2; ++m2) {
          const int mi = mh * 2 + m2;
          floatx4 sa = (floatx4){0.f, 0.f, 0.f, 0.f};
          floatx4 sb = (floatx4){0.f, 0.f, 0.f, 0.f};
          sa = __builtin_amdgcn_mfma_f32_16x16x32_bf16(ka0, qf[mi][0], sa, 0, 0, 0);
          sa = __builtin_amdgcn_mfma_f32_16x16x32_bf16(ka1, qf[mi][1], sa, 0, 0, 0);
          sb = __builtin_amdgcn_mfma_f32_16x16x32_bf16(kb0, qf[mi][0], sb, 0, 0, 0);
          sb = __builtin_amdgcn_mfma_f32_16x16x32_bf16(kb1, qf[mi][1], sb, 0, 0, 0);
          const float C = 0.18033688011112042f;  // 0.125 * log2(e)
          float e0 = exp2f(sa[0] * C), e1 = exp2f(sa[1] * C);
          float e2 = exp2f(sa[2] * C), e3 = exp2f(sa[3] * C);
          float f0 = exp2f(sb[0] * C), f1 = exp2f(sb[1] * C);
          float f2 = exp2f(sb[2] * C), f3 = exp2f(sb[3] * C);
          lsum[mi] += ((e0 + e1) + (e2 + e3)) + ((f0 + f1) + (f2 + f3));
          unsigned wa0 = cvt_pk_bf16(e0, e1), wa1 = cvt_pk_bf16(e2, e3);
          unsigned wb0 = cvt_pk_bf16(f0, f1), wb1 = cvt_pk_bf16(f2, f3);
          uint2v r0 = permswap32(wa0, wb0);
          uint2v r1 = permswap32(wa1, wb1);
          pa0[m2][2 * nl + 0] = r0.x; pa1[m2][2 * nl + 0] = r0.y;
          pa0[m2][2 * nl + 1] = r1.x; pa1[m2][2 * nl + 1] = r1.y;
        }
      }
      // ---- PV for this mi pair
#pragma unroll
      for (int kh = 0; kh < 2; ++kh)
#pragma unroll
        for (int ni = 0; ni < 4; ++ni) {
          const short8 vf = *(const short8*)&Bf[kh ? (voff[ni] ^ 32) : voff[ni]];
#pragma unroll
          for (int m2 = 0; m2 < 2; ++m2) {
            union { uintx4 u; short8 s; } cv;
            cv.u = kh ? (uintx4){pa1[m2][0], pa1[m2][1], pa1[m2][2], pa1[m2][3]}
                      : (uintx4){pa0[m2][0], pa0[m2][1], pa0[m2][2], pa0[m2][3]};
            oacc[mh * 2 + m2][ni] =
                __builtin_amdgcn_mfma_f32_16x16x32_bf16(cv.s, vf, oacc[mh * 2 + m2][ni], 0, 0, 0);
          }
        }
    }
    __syncthreads();
  }

  // ---- epilogue: O through LDS for coalesced stores (smem fully free now)
  unsigned short* Cs = &smem[0][0];  // [256 q][64 d] bf16 = 32KB
#pragma unroll
  for (int mi = 0; mi < 4; mi++)
#pragma unroll
    for (int ni = 0; ni < 4; ni++)
#pragma unroll
      for (int p = 0; p < 4; p++) {
        int q = wave * 64 + mi * 16 + quad * 4 + p;
        int d = ni * 16 + l16;
        int cc = d >> 3;
        Cs[q * 64 + ((cc ^ (q & 7)) * 8) + (d & 7)] = f2b(oacc[mi][ni][p]);
      }
  __syncthreads();
  unsigned short* Ob = Onum + ((size_t)bh * NS + split) * 256 * 64;
#pragma unroll
  for (int i = 0; i < 8; ++i) {
    int q = (tid >> 3) + 32 * i;
    int cc = tid & 7;
    short8 v = *(const short8*)&Cs[q * 64 + ((cc ^ (q & 7)) * 8)];
    *(short8*)&Ob[q * 64 + cc * 8] = v;
  }
  // ---- l: reduce across quads (same q lives at all 4 quads of an l16)
#pragma unroll
  for (int mi = 0; mi < 4; ++mi) {
    float v = lsum[mi];
    v += __shfl_xor(v, 16, 64);
    v += __shfl_xor(v, 32, 64);
    lsum[mi] = v;
  }
  if (quad == 0) {
    float* lb = lpart + ((size_t)bh * NS + split) * 256;
#pragma unroll
    for (int mi = 0; mi < 4; ++mi)
      lb[wave * 64 + mi * 16 + l16] = lsum[mi];
  }
}

// ---------------- reduce: ho[b, h*64+d] = mean_q( sum_s O / sum_s l ) --------
__global__ __launch_bounds__(256) void reduce_heads_kernel(
    const unsigned short* __restrict__ Onum, const float* __restrict__ lpart,
    float* __restrict__ ho) {
  const int bh = blockIdx.x;
  const int t = threadIdx.x;
  __shared__ float ls[256];
  __shared__ float red[16][64];
  float l = 0.f;
#pragma unroll
  for (int s = 0; s < NS; s++) l += lpart[((size_t)bh * NS + s) * 256 + t];
  ls[t] = l;
  __syncthreads();
  const int d4 = t & 15, qg = t >> 4;
  float4 part = {0.f, 0.f, 0.f, 0.f};
  for (int qi = 0; qi < 16; ++qi) {
    int q = qg * 16 + qi;
    float4 on = {0.f, 0.f, 0.f, 0.f};
#pragma unroll
    for (int s = 0; s < NS; s++) {
      ushort4 v = *(const ushort4*)&Onum[(((size_t)bh * NS + s) * 256 + q) * 64 + d4 * 4];
      on.x += b2f(v.x); on.y += b2f(v.y); on.z += b2f(v.z); on.w += b2f(v.w);
    }
    const float rl = 1.f / ls[q];
    part.x += on.x * rl; part.y += on.y * rl;
    part.z += on.z * rl; part.w += on.w * rl;
  }
  *(float4*)&red[qg][d4 * 4] = part;
  __syncthreads();
  if (t < 64) {
    float v = 0.f;
#pragma unroll
    for (int r = 0; r < 16; ++r) v += red[r][t];
    v *= (1.f / 256.f);
    int b = bh >> 4, h = bh & 15;
    ho[b * 1024 + h * 64 + t] = v;
  }
}

// ---------------- gs[b,c] = bo[c] + sum_k Wo[c,k] * ho[b,k] ------------------
__global__ __launch_bounds__(256) void wo_proj_kernel(
    const float* __restrict__ ho, const float* __restrict__ Wo,
    const float* __restrict__ bo, float* __restrict__ gs) {
  const int b = blockIdx.x >> 2, cg = blockIdx.x & 3;
  const int t = threadIdx.x;
  __shared__ float hs[1024];
#pragma unroll
  for (int i = 0; i < 4; i++) hs[t + i * 256] = ho[b * 1024 + t + i * 256];
  __syncthreads();
  const int c = cg * 256 + t;
  const float* wrow = Wo + (size_t)c * 1024;
  float acc = bo[c];
  for (int k = 0; k < 1024; k += 4) {
    float4 w4 = *(const float4*)&wrow[k];
    acc += w4.x * hs[k] + w4.y * hs[k + 1] + w4.z * hs[k + 2] + w4.w * hs[k + 3];
  }
  gs[b * 1024 + c] = acc;
}

// ---------------- out = x + a * gs[b,:] --------------------------------------
__global__ __launch_bounds__(256) void final_add_kernel(
    const float* __restrict__ x, const float* __restrict__ gs,
    const float* __restrict__ alpha, float* __restrict__ out) {
  const float a = 0.3f / (1.f + __expf(-alpha[0]));
  const size_t i4 = (size_t)blockIdx.x * 256 + threadIdx.x;
  const float4 xv = ((const float4*)x)[i4];
  const float4 g = *(const float4*)&gs[(i4 >> 20) * 1024 + (i4 & 255) * 4];
  float4 o;
  o.x = xv.x + a * g.x; o.y = xv.y + a * g.y;
  o.z = xv.z + a * g.z; o.w = xv.w + a * g.w;
  ((float4*)out)[i4] = o;
}

extern "C" void kernel_launch(void* const* d_in, const int* in_sizes, int n_in,
                              void* d_out, int out_size, void* d_ws, size_t ws_size,
                              hipStream_t stream) {
  const float* prompt = (const float*)d_in[0];
  const float* x      = (const float*)d_in[1];
  const float* lnqw   = (const float*)d_in[2];
  const float* lnqb   = (const float*)d_in[3];
  const float* lnkw   = (const float*)d_in[4];
  const float* lnkb   = (const float*)d_in[5];
  const float* Wq     = (const float*)d_in[6];
  const float* bq     = (const float*)d_in[7];
  const float* Wk     = (const float*)d_in[8];
  const float* bk     = (const float*)d_in[9];
  const float* Wo     = (const float*)d_in[10];
  const float* bo     = (const float*)d_in[11];
  const float* alpha  = (const float*)d_in[12];
  float* out = (float*)d_out;

  char* ws = (char*)d_ws;
  // kln and Vbf share the first 64 MB: kln fully consumed by the K-GEMM
  // before vtrans_kernel overwrites the region (stream-ordered).
  unsigned short* kln = (unsigned short*)(ws + 0);            // 64 MB
  unsigned short* Vbf = (unsigned short*)(ws + 0);            // 64 MB (after)
  unsigned short* qln = (unsigned short*)(ws + 67108864);     // 4 MB
  unsigned short* Wqb = (unsigned short*)(ws + 71303168);     // 2 MB
  unsigned short* Wkb = (unsigned short*)(ws + 73400320);     // 2 MB
  unsigned short* Qp  = (unsigned short*)(ws + 75497472);     // 4 MB
  float* lpart        = (float*)(ws + 79691776);              // 1 MB
  float* ho           = (float*)(ws + 80740352);              // 32 KB
  float* gs           = (float*)(ws + 80773120);              // 32 KB

  // d_out scratch: Kp (64 MB) + Onum bf16 (33.5 MB); both consumed before
  // final_add_kernel overwrites d_out.
  char* ob = (char*)d_out;
  unsigned short* Kp   = (unsigned short*)(ob + 0);           // 64 MB
  unsigned short* Onum = (unsigned short*)(ob + 67108864);    // 33.5 MB

  ln_bf16_kernel<<<32768, 256, 0, stream>>>(x, lnkw, lnkb, kln);
  ln_bf16_kernel<<<2048, 256, 0, stream>>>(prompt, lnqw, lnqb, qln);
  conv_bf16_kernel<<<1024, 256, 0, stream>>>(Wq, Wqb);
  conv_bf16_kernel<<<1024, 256, 0, stream>>>(Wk, Wkb);
  gemm_bt_kernel<<<128, 256, 0, stream>>>(qln, Wqb, bq, Qp, 2048);
  gemm_bt_kernel<<<2048, 256, 0, stream>>>(kln, Wkb, bk, Kp, 32768);
  vtrans_kernel<<<dim3(128, 16), 256, 0, stream>>>(x, Vbf);
  attn_kernel<<<dim3(128, NS), 256, 0, stream>>>(Qp, Kp, Vbf, Onum, lpart);
  reduce_heads_kernel<<<128, 256, 0, stream>>>(Onum, lpart, ho);
  wo_proj_kernel<<<32, 256, 0, stream>>>(ho, Wo, bo, gs);
  final_add_kernel<<<32768, 256, 0, stream>>>(x, gs, alpha, out);
}